// Round 2
// baseline (196.839 us; speedup 1.0000x reference)
//
#include <hip/hip_runtime.h>

using u16 = unsigned short;
using u32 = unsigned int;

typedef __attribute__((ext_vector_type(8))) _Float16 f16x8;
typedef __attribute__((ext_vector_type(4))) float floatx4;

#define NTOK 512
#define DIM  256   // NODE_DIM == HIDDEN
#define EDIM 128

// ---------------------------------------------------------------------------
// Kernel 1: LayerNorm + proj (q,k) + qd/kd pre-GEMMs.  4 rows per block.
// Inputs f32.  Outputs: q,k as f16 [512][256]; qdb = q@w_d^T + o_b (f32),
// kd = k@w_d^T (f32).
// ---------------------------------------------------------------------------
__global__ __launch_bounds__(256) void k1_ln_proj(
    const float* __restrict__ node, const float* __restrict__ ln_w,
    const float* __restrict__ ln_b, const float* __restrict__ proj_w,
    const float* __restrict__ proj_b, const float* __restrict__ o_w,
    const float* __restrict__ o_b,
    u16* __restrict__ qo, u16* __restrict__ ko,
    float* __restrict__ qdb, float* __restrict__ kdo)
{
    __shared__ float sn[4][DIM];       // normalized rows
    __shared__ float sfull[4][2*DIM];  // s = LN@proj_w^T + proj_b (q|k concat)
    const int tid  = threadIdx.x;
    const int wid  = tid >> 6;
    const int lane = tid & 63;
    const int n0   = blockIdx.x * 4;

    // --- LayerNorm: wave w -> row n0+w ---
    {
        const int n = n0 + wid;
        const int d = lane * 4;
        const float4 x = *(const float4*)(node + n*DIM + d);
        float s  = x.x + x.y + x.z + x.w;
        float ss = x.x*x.x + x.y*x.y + x.z*x.z + x.w*x.w;
        #pragma unroll
        for (int off = 32; off > 0; off >>= 1) {
            s  += __shfl_xor(s,  off);
            ss += __shfl_xor(ss, off);
        }
        const float mu   = s * (1.0f/DIM);
        const float var  = ss * (1.0f/DIM) - mu*mu;
        const float rstd = rsqrtf(var + 1e-5f);
        const float4 w = *(const float4*)(ln_w + d);
        const float4 b = *(const float4*)(ln_b + d);
        sn[wid][d+0] = (x.x-mu)*rstd*w.x + b.x;
        sn[wid][d+1] = (x.y-mu)*rstd*w.y + b.y;
        sn[wid][d+2] = (x.z-mu)*rstd*w.z + b.z;
        sn[wid][d+3] = (x.w-mu)*rstd*w.w + b.w;
    }
    __syncthreads();

    // --- proj: thread t computes cols c0=t (q) and c1=t+256 (k), 4 rows ---
    {
        const int c0 = tid, c1 = tid + DIM;
        const float bq = proj_b[c0], bk = proj_b[c1];
        float accq[4], acck[4];
        #pragma unroll
        for (int r = 0; r < 4; ++r) { accq[r] = bq; acck[r] = bk; }
        const float* w0p = proj_w + c0*DIM;
        const float* w1p = proj_w + c1*DIM;
        for (int d = 0; d < DIM; d += 4) {
            const float4 wa = *(const float4*)(w0p + d);
            const float4 wb = *(const float4*)(w1p + d);
            #pragma unroll
            for (int r = 0; r < 4; ++r) {
                const float s0 = sn[r][d+0], s1 = sn[r][d+1];
                const float s2 = sn[r][d+2], s3 = sn[r][d+3];
                accq[r] += wa.x*s0 + wa.y*s1 + wa.z*s2 + wa.w*s3;
                acck[r] += wb.x*s0 + wb.y*s1 + wb.z*s2 + wb.w*s3;
            }
        }
        #pragma unroll
        for (int r = 0; r < 4; ++r) {
            sfull[r][c0] = accq[r];
            sfull[r][c1] = acck[r];
            qo[(n0+r)*DIM + c0] = __builtin_bit_cast(u16, (_Float16)accq[r]);
            ko[(n0+r)*DIM + c0] = __builtin_bit_cast(u16, (_Float16)acck[r]);
        }
    }
    __syncthreads();

    // --- qd[n,e] = q[n,:]·w_d[e,:] + o_b[e] ;  kd[n,e] = k[n,:]·w_d[e,:] ---
    {
        const int e    = tid & (EDIM-1);
        const int half = tid >> 7;             // 0: qd (q part), 1: kd (k part)
        const float* wd = o_w + e*(2*DIM) + DIM;  // w_d = o_w[:, 256:512]
        float a[4] = {0.f, 0.f, 0.f, 0.f};
        for (int h = 0; h < DIM; h += 4) {
            const float4 w = *(const float4*)(wd + h);
            #pragma unroll
            for (int r = 0; r < 4; ++r) {
                const float* sp = &sfull[r][half*DIM + h];
                a[r] += w.x*sp[0] + w.y*sp[1] + w.z*sp[2] + w.w*sp[3];
            }
        }
        if (half == 0) {
            const float ob = o_b[e];
            #pragma unroll
            for (int r = 0; r < 4; ++r) qdb[(n0+r)*EDIM + e] = a[r] + ob;
        } else {
            #pragma unroll
            for (int r = 0; r < 4; ++r) kdo[(n0+r)*EDIM + e] = a[r];
        }
    }
}

// ---------------------------------------------------------------------------
// Kernel 2: x[i,j,e] = (q[j,:]*k[i,:])·w_p[e,:] + qd[j,e] - kd[i,e]
// Grid: 256 blocks = 4 j-tiles(128) x 64 i-groups(8).  256 thr = 4 waves,
// each wave owns a 64j x 64e register tile (4x4 MFMA 16x16x32_f16 tiles).
// q-frags (f16) and w_p-frags (f16) persist in registers across the i-loop;
// per-i work: v_pk_mul_f16 scale of A-frags by k[i,:], 128 MFMAs, 64 f32
// stores.  Store-BW-bound by design (128 MB f32 output).
// ---------------------------------------------------------------------------
__global__ __launch_bounds__(256, 1) void k2_edge(
    const u16* __restrict__ qg, const u16* __restrict__ kg,
    const float* __restrict__ qdb, const float* __restrict__ kdg,
    const float* __restrict__ o_w, float* __restrict__ outp)
{
    const int tid  = threadIdx.x;
    const int wid  = tid >> 6;
    const int lane = tid & 63;
    const int col  = lane & 15;
    const int quad = lane >> 4;
    const int bid  = blockIdx.x;
    const int j0 = (bid & 3) * 128 + (wid & 1) * 64;
    const int e0 = (wid >> 1) * 64;
    const int i0 = (bid >> 2) * 8;

    // B-fragments: w_p[e][h] = o_w[e*512 + h], h in [0,256), f32 -> f16
    f16x8 bfr[4][8];
    #pragma unroll
    for (int et = 0; et < 4; ++et) {
        const float* p = o_w + (e0 + et*16 + col) * 512 + quad*8;
        #pragma unroll
        for (int ks = 0; ks < 8; ++ks) {
            const float4 lo = *(const float4*)(p + ks*32);
            const float4 hi = *(const float4*)(p + ks*32 + 4);
            f16x8 v;
            v[0] = (_Float16)lo.x; v[1] = (_Float16)lo.y;
            v[2] = (_Float16)lo.z; v[3] = (_Float16)lo.w;
            v[4] = (_Float16)hi.x; v[5] = (_Float16)hi.y;
            v[6] = (_Float16)hi.z; v[7] = (_Float16)hi.w;
            bfr[et][ks] = v;
        }
    }
    // A-fragments: q[j][h] (already f16 in workspace)
    f16x8 afr[4][8];
    #pragma unroll
    for (int mt = 0; mt < 4; ++mt) {
        const u16* p = qg + (j0 + mt*16 + col) * 256 + quad*8;
        #pragma unroll
        for (int ks = 0; ks < 8; ++ks)
            afr[mt][ks] = __builtin_bit_cast(f16x8, *(const uint4*)(p + ks*32));
    }
    // qd (+o_b) in C-layout — i-independent part of the accumulator init
    floatx4 qiv[4][4];
    #pragma unroll
    for (int mt = 0; mt < 4; ++mt) {
        #pragma unroll
        for (int et = 0; et < 4; ++et) {
            const int ec = e0 + et*16 + col;
            #pragma unroll
            for (int r = 0; r < 4; ++r)
                qiv[mt][et][r] = qdb[(j0 + mt*16 + quad*4 + r) * EDIM + ec];
        }
    }

    #pragma unroll 1
    for (int i = i0; i < i0 + 8; ++i) {
        float kdv[4];
        #pragma unroll
        for (int et = 0; et < 4; ++et)
            kdv[et] = kdg[i*EDIM + e0 + et*16 + col];

        floatx4 acc[4][4];
        #pragma unroll
        for (int mt = 0; mt < 4; ++mt)
            #pragma unroll
            for (int et = 0; et < 4; ++et)
                acc[mt][et] = qiv[mt][et] - kdv[et];

        const u16* kp = kg + i*256 + quad*8;
        #pragma unroll
        for (int ks = 0; ks < 8; ++ks) {
            const f16x8 kv = __builtin_bit_cast(f16x8, *(const uint4*)(kp + ks*32));
            #pragma unroll
            for (int mt = 0; mt < 4; ++mt) {
                const f16x8 sa = afr[mt][ks] * kv;   // v_pk_mul_f16 x4
                #pragma unroll
                for (int et = 0; et < 4; ++et)
                    acc[mt][et] = __builtin_amdgcn_mfma_f32_16x16x32_f16(
                        sa, bfr[et][ks], acc[mt][et], 0, 0, 0);
            }
        }

        float* ob = outp + (size_t)i * (NTOK * EDIM);
        #pragma unroll
        for (int mt = 0; mt < 4; ++mt) {
            #pragma unroll
            for (int et = 0; et < 4; ++et) {
                const int ec = e0 + et*16 + col;
                #pragma unroll
                for (int r = 0; r < 4; ++r)
                    ob[(j0 + mt*16 + quad*4 + r) * EDIM + ec] = acc[mt][et][r];
            }
        }
    }
}

extern "C" void kernel_launch(void* const* d_in, const int* in_sizes, int n_in,
                              void* d_out, int out_size, void* d_ws, size_t ws_size,
                              hipStream_t stream) {
    const float* node   = (const float*)d_in[0];
    const float* ln_w   = (const float*)d_in[1];
    const float* ln_b   = (const float*)d_in[2];
    const float* proj_w = (const float*)d_in[3];
    const float* proj_b = (const float*)d_in[4];
    const float* o_w    = (const float*)d_in[5];
    const float* o_b    = (const float*)d_in[6];
    float* outp = (float*)d_out;

    // ws layout: q f16 [512][256] | k f16 [512][256] | qdb f32 [512][128] | kd f32 [512][128]
    u16*   qws = (u16*)d_ws;
    u16*   kws = qws + NTOK*DIM;
    float* qdb = (float*)(kws + NTOK*DIM);
    float* kdw = qdb + NTOK*EDIM;

    hipLaunchKernelGGL(k1_ln_proj, dim3(NTOK/4), dim3(256), 0, stream,
                       node, ln_w, ln_b, proj_w, proj_b, o_w, o_b, qws, kws, qdb, kdw);
    hipLaunchKernelGGL(k2_edge, dim3(256), dim3(256), 0, stream,
                       qws, kws, qdb, kdw, o_w, outp);
}